// Round 13
// baseline (165.113 us; speedup 1.0000x reference)
//
#include <hip/hip_runtime.h>

#define NA 1000
#define NCH 3
#define CHMAX 336              // chunk lengths: 336, 336, 328 (all % 8 == 0)
#define ND 513
#define ND2 512                // pair cells per angle: d in [0,511]
#define CROP 362
#define TOP 75                 // (512-362)/2
#define NPIX (CROP * CROP)     // 131044
#define NTILE 23               // ceil(362/16)
#define GRP 8                  // angles per staged group
#define WIN 32                 // detector cells per staged window

// rotation by 4*dtheta = 4*pi/1000 (f32 literals from double eval)
#define C4R 0.9999210442038161f
#define S4R 0.0125660398933523f

typedef __fp16 half2_t __attribute__((ext_vector_type(2)));

// Static device buffers, fully rewritten every call (deterministic).
// g_plo[a*512+d]  = 16 B: f16 pairs (x[b][a][d], x[b][a][d+1]) b=0..3  (LDS path)
// g_pmid[a*512+d] =  8 B: pairs b=4..5                                  (LDS path)
// g_p67[a*512+d]  =  8 B: pairs b=6..7                                  (L1 path)
__device__ float2 g_tab[NA];
__device__ uint4  g_plo[(size_t)NA * ND2];
__device__ uint2  g_pmid[(size_t)NA * ND2];
__device__ uint2  g_p67[(size_t)NA * ND2];
__device__ float  g_part[(size_t)NCH * 8 * NPIX];

__global__ void table_kernel() {
    int a = blockIdx.x * blockDim.x + threadIdx.x;
    if (a >= NA) return;
    double th = (double)a * (3.14159265358979323846 / (double)NA);
    float delta_f = (float)(2.0 * 0.13 / (double)(ND - 1));
    double inv = 1.0 / (double)delta_f;
    g_tab[a] = make_float2((float)(cos(th) * inv), (float)(sin(th) * inv));
}

// x[b][a][d] (b-major, f32) -> pre-assembled f16 interp pairs, 3 arrays.
__global__ void pack_kernel(const float* __restrict__ x) {
    int t = blockIdx.x * blockDim.x + threadIdx.x;   // t = a*512 + d
    if (t >= NA * ND2) return;
    int a = t >> 9, d = t & 511;
    const float* p0 = x + (size_t)a * ND + d;
    const int S = NA * ND;
    unsigned int w[8];
    #pragma unroll
    for (int b = 0; b < 8; ++b) {
        half2_t h;
        h.x = (__fp16)p0[(size_t)b * S];
        h.y = (__fp16)p0[(size_t)b * S + 1];
        __builtin_memcpy(&w[b], &h, 4);
    }
    g_plo[t]  = make_uint4(w[0], w[1], w[2], w[3]);
    g_pmid[t] = make_uint2(w[4], w[5]);
    g_p67[t]  = make_uint2(w[6], w[7]);
}

__device__ __forceinline__ float dot2(unsigned int pair, half2_t wp, float acc) {
    half2_t h; __builtin_memcpy(&h, &pair, 4);
    float d;
    asm("v_dot2_f32_f16 %0, %1, %2, %3" : "=v"(d) : "v"(h), "v"(wp), "v"(acc));
    return d;
}

// grid (23,23,3) = 1587 blocks (all-resident at 8 blocks/CU); block 256.
// Wave = 8x8 pixel patch. b0-5 gathered from LDS windows, b6-7 from global L1.
__global__ __launch_bounds__(256, 8) void bp_kernel() {
    __shared__ uint4  s_lo[2][GRP * WIN];   // 8 KB
    __shared__ uint2  s_mid[2][GRP * WIN];  // 4 KB
    __shared__ float2 s_tab[CHMAX];         // 2.7 KB
    __shared__ int    s_base[CHMAX];        // 1.4 KB

    int ch  = blockIdx.z;
    int A0  = ch * CHMAX;
    int len = min(CHMAX, NA - A0);          // 336 or 328
    int ngrp = len >> 3;
    int tid = threadIdx.x;
    int bi  = blockIdx.y, bj = blockIdx.x;

    const float step = (float)(0.26 / 511.0);

    // ---- per-angle window bases (corner-min p, 2-cell guard) + tab copy ----
    float Xa = fmaf((float)(TOP + bi * 16),      step, -0.13f);
    float Xb = fmaf((float)(TOP + bi * 16 + 15), step, -0.13f);
    float Ya = fmaf((float)(TOP + bj * 16),      step, -0.13f);
    float Yb = fmaf((float)(TOP + bj * 16 + 15), step, -0.13f);
    for (int aidx = tid; aidx < len; aidx += 256) {
        float2 cs = g_tab[A0 + aidx];
        s_tab[aidx] = cs;
        float p0 = fmaf(Xa, cs.x, fmaf(Ya, cs.y, 256.0f));
        float p1 = fmaf(Xb, cs.x, fmaf(Ya, cs.y, 256.0f));
        float p2 = fmaf(Xa, cs.x, fmaf(Yb, cs.y, 256.0f));
        float p3 = fmaf(Xb, cs.x, fmaf(Yb, cs.y, 256.0f));
        float pm = fminf(fminf(p0, p1), fminf(p2, p3)) - 2.0f;
        int b = (int)floorf(pm);
        b = b < 0 ? 0 : b;
        b = b > (ND2 - WIN) ? (ND2 - WIN) : b;   // [0, 480]
        s_base[aidx] = b;
    }
    __syncthreads();

    // ---- pixel coords ----
    int wave = tid >> 6, lane = tid & 63;
    int i = bi * 16 + (wave >> 1) * 8 + (lane >> 3);   // -> X
    int j = bj * 16 + (wave & 1) * 8 + (lane & 7);     // -> Y
    int ic = min(i, CROP - 1), jc = min(j, CROP - 1);
    float X = fmaf((float)(TOP + ic), step, -0.13f);
    float Y = fmaf((float)(TOP + jc), step, -0.13f);

    // staging address pieces (thread t stages cell sl of group-angle sk)
    int sk = tid >> 5, sl = tid & 31;

    // ---- prologue: stage group 0 into buffer 0 ----
    {
        size_t idx = (size_t)(A0 + sk) * ND2 + s_base[sk] + sl;
        s_lo[0][tid]  = g_plo[idx];
        s_mid[0][tid] = g_pmid[idx];
    }
    __syncthreads();

    float acc0 = 0.f, acc1 = 0.f, acc2 = 0.f, acc3 = 0.f;
    float acc4 = 0.f, acc5 = 0.f, acc6 = 0.f, acc7 = 0.f;

#define BODY(K, BASE, CC, SS)                                           \
    {                                                                   \
        float p  = fmaf(X, CC, fmaf(Y, SS, 256.0f));                    \
        float fi = floorf(p);                                           \
        float w  = p - fi;                                              \
        half2_t wp = __builtin_amdgcn_cvt_pkrtz(1.0f - w, w);           \
        int i0 = (int)fi;                                               \
        int l  = i0 - (BASE);                                           \
        uint4 lo = blo[(K) * WIN + l];                                  \
        uint2 md = bmd[(K) * WIN + l];                                  \
        uint2 hi = grow[((K) << 9) + i0];                               \
        acc0 = dot2(lo.x, wp, acc0);                                    \
        acc1 = dot2(lo.y, wp, acc1);                                    \
        acc2 = dot2(lo.z, wp, acc2);                                    \
        acc3 = dot2(lo.w, wp, acc3);                                    \
        acc4 = dot2(md.x, wp, acc4);                                    \
        acc5 = dot2(md.y, wp, acc5);                                    \
        acc6 = dot2(hi.x, wp, acc6);                                    \
        acc7 = dot2(hi.y, wp, acc7);                                    \
    }

    for (int g = 0; g < ngrp; ++g) {
        int cur = g & 1;
        bool have = (g + 1) < ngrp;
        uint4 r0; uint2 r1;
        if (have) {
            int ag = (g + 1) * GRP + sk;
            size_t idx = (size_t)(A0 + ag) * ND2 + s_base[ag] + sl;
            r0 = g_plo[idx];
            r1 = g_pmid[idx];
        }

        const uint4* blo = s_lo[cur];
        const uint2* bmd = s_mid[cur];
        int gb = g * GRP;
        const uint2* __restrict__ grow = g_p67 + ((size_t)(A0 + gb) << 9);

        // uniform per-group broadcasts: 8 bases + 4 (cos,sin); rotate for +4
        int4  b4a = *(const int4*)(s_base + gb);
        int4  b4b = *(const int4*)(s_base + gb + 4);
        float4 t01 = *(const float4*)(s_tab + gb);
        float4 t23 = *(const float4*)(s_tab + gb + 2);
        float c_0 = t01.x, s_0 = t01.y, c_1 = t01.z, s_1 = t01.w;
        float c_2 = t23.x, s_2 = t23.y, c_3 = t23.z, s_3 = t23.w;
        float c_4 = fmaf(c_0, C4R, -(s_0 * S4R)), s_4 = fmaf(c_0, S4R, s_0 * C4R);
        float c_5 = fmaf(c_1, C4R, -(s_1 * S4R)), s_5 = fmaf(c_1, S4R, s_1 * C4R);
        float c_6 = fmaf(c_2, C4R, -(s_2 * S4R)), s_6 = fmaf(c_2, S4R, s_2 * C4R);
        float c_7 = fmaf(c_3, C4R, -(s_3 * S4R)), s_7 = fmaf(c_3, S4R, s_3 * C4R);

        BODY(0, b4a.x, c_0, s_0)
        BODY(1, b4a.y, c_1, s_1)
        BODY(2, b4a.z, c_2, s_2)
        BODY(3, b4a.w, c_3, s_3)
        BODY(4, b4b.x, c_4, s_4)
        BODY(5, b4b.y, c_5, s_5)
        BODY(6, b4b.z, c_6, s_6)
        BODY(7, b4b.w, c_7, s_7)

        if (have) {
            int nxt = cur ^ 1;
            s_lo[nxt][tid]  = r0;
            s_mid[nxt][tid] = r1;
        }
        __syncthreads();
    }
#undef BODY

    if (i < CROP && j < CROP) {
        float* p0 = g_part + (size_t)ch * 8 * NPIX + (size_t)i * CROP + j;
        p0[0 * NPIX] = acc0; p0[1 * NPIX] = acc1;
        p0[2 * NPIX] = acc2; p0[3 * NPIX] = acc3;
        p0[4 * NPIX] = acc4; p0[5 * NPIX] = acc5;
        p0[6 * NPIX] = acc6; p0[7 * NPIX] = acc7;
    }
}

// out[b][pix] = sum_ch part[ch][b][pix] * pi/NA
__global__ void combine_kernel(float* __restrict__ out) {
    int t = blockIdx.x * 256 + threadIdx.x;      // t over 8*NPIX, batch-major
    if (t >= 8 * NPIX) return;
    const float scale = (float)(3.14159265358979323846 / 1000.0);
    float s = 0.f;
    #pragma unroll
    for (int ch = 0; ch < NCH; ++ch) s += g_part[(size_t)ch * 8 * NPIX + t];
    out[t] = s * scale;
}

extern "C" void kernel_launch(void* const* d_in, const int* in_sizes, int n_in,
                              void* d_out, int out_size, void* d_ws, size_t ws_size,
                              hipStream_t stream) {
    const float* x = (const float*)d_in[0];
    float* out = (float*)d_out;

    table_kernel<<<(NA + 255) / 256, 256, 0, stream>>>();
    pack_kernel<<<(NA * ND2 + 255) / 256, 256, 0, stream>>>(x);

    dim3 bgrid(NTILE, NTILE, NCH);
    bp_kernel<<<bgrid, 256, 0, stream>>>();

    combine_kernel<<<(8 * NPIX + 255) / 256, 256, 0, stream>>>(out);
}

// Round 14
// 142.731 us; speedup vs baseline: 1.1568x; 1.1568x over previous
//
#include <hip/hip_runtime.h>

#define NA 1000
#define CHA 288                // angles per LDS-path chunk (slots 0,1): %8==0
#define A0B 576                // L1-path chunk start (slot 2)
#define LENB 424               // L1-path chunk length
#define ND 513
#define ND2 512                // pair cells per angle: d in [0,511]
#define CROP 362
#define TOP 75                 // (512-362)/2
#define NPIX (CROP * CROP)     // 131044
#define NTILE 23               // ceil(362/16)
#define GRP 8                  // angles per staged group (LDS path)
#define WIN 32                 // detector cells per staged window

// rotation by 4*dtheta = 4*pi/1000 (f32 literals from double eval)
#define C4R 0.9999210442038161f
#define S4R 0.0125660398933523f

typedef __fp16 half2_t __attribute__((ext_vector_type(2)));

// Static device buffers, fully rewritten every call (deterministic).
// g_plo[a*512+d] = 16 B: f16 pairs (x[b][a][d], x[b][a][d+1]) for b=0..3.
// g_phi: same for b=4..7.  g_part: [slot][batch][pix] f32 partials.
__device__ float2 g_tab[NA];
__device__ uint4  g_plo[(size_t)NA * ND2];
__device__ uint4  g_phi[(size_t)NA * ND2];
__device__ float  g_part[(size_t)3 * 8 * NPIX];

__global__ void table_kernel() {
    int a = blockIdx.x * blockDim.x + threadIdx.x;
    if (a >= NA) return;
    double th = (double)a * (3.14159265358979323846 / (double)NA);
    float delta_f = (float)(2.0 * 0.13 / (double)(ND - 1));
    double inv = 1.0 / (double)delta_f;
    g_tab[a] = make_float2((float)(cos(th) * inv), (float)(sin(th) * inv));
}

// x[b][a][d] (b-major, f32) -> pre-assembled f16 interp pairs.
__global__ void pack_kernel(const float* __restrict__ x) {
    int t = blockIdx.x * blockDim.x + threadIdx.x;   // t = a*512 + d
    if (t >= NA * ND2) return;
    int a = t >> 9, d = t & 511;
    const float* p0 = x + (size_t)a * ND + d;
    const int S = NA * ND;
    unsigned int w[8];
    #pragma unroll
    for (int b = 0; b < 8; ++b) {
        half2_t h;
        h.x = (__fp16)p0[(size_t)b * S];
        h.y = (__fp16)p0[(size_t)b * S + 1];
        __builtin_memcpy(&w[b], &h, 4);
    }
    g_plo[t] = make_uint4(w[0], w[1], w[2], w[3]);
    g_phi[t] = make_uint4(w[4], w[5], w[6], w[7]);
}

__device__ __forceinline__ float dot2(unsigned int pair, half2_t wp, float acc) {
    half2_t h; __builtin_memcpy(&h, &pair, 4);
    float d;
    asm("v_dot2_f32_f16 %0, %1, %2, %3" : "=v"(d) : "v"(h), "v"(wp), "v"(acc));
    return d;
}

// grid (3, 23, 23): blockIdx.x = slot (fastest-varying -> 2:1 interleaved
// dispatch). Slots 0,1 = LDS-gather path (angles [0,576), R9 structure).
// Slot 2 = L1-gather path (angles [576,1000), R5 structure). Both pipe
// families run concurrently on each CU. Block 256 = 4 waves of 8x8 patches.
__global__ __launch_bounds__(256, 8) void bp_kernel() {
    __shared__ uint4  s_lo[2][GRP * WIN];   // 8 KB   (A path)
    __shared__ uint4  s_hi[2][GRP * WIN];   // 8 KB   (A path)
    __shared__ int    s_base[CHA];          // 1.2 KB (A path)
    __shared__ float2 s_tab[CHA];           // 2.3 KB (A path)

    int slot = blockIdx.x;
    int tid  = threadIdx.x;
    int bi   = blockIdx.z, bj = blockIdx.y;

    const float step = (float)(0.26 / 511.0);

    // ---- pixel coords (both paths) ----
    int wave = tid >> 6, lane = tid & 63;
    int i = bi * 16 + (wave >> 1) * 8 + (lane >> 3);   // -> X
    int j = bj * 16 + (wave & 1) * 8 + (lane & 7);     // -> Y
    int ic = min(i, CROP - 1), jc = min(j, CROP - 1);
    float X = fmaf((float)(TOP + ic), step, -0.13f);
    float Y = fmaf((float)(TOP + jc), step, -0.13f);

    float acc0 = 0.f, acc1 = 0.f, acc2 = 0.f, acc3 = 0.f;
    float acc4 = 0.f, acc5 = 0.f, acc6 = 0.f, acc7 = 0.f;

    if (slot == 2) {
        // ================= L1-gather path (R5 structure) =================
        float2* s_tb = (float2*)s_lo;   // overlay: A-path buffers unused here
        for (int aidx = tid; aidx < LENB; aidx += 256)
            s_tb[aidx] = g_tab[A0B + aidx];
        __syncthreads();

        const uint4* __restrict__ plo = g_plo + ((size_t)A0B << 9);
        const uint4* __restrict__ phi = g_phi + ((size_t)A0B << 9);

        for (int a = 0; a < LENB; ++a) {
            float2 cs = s_tb[a];
            float p  = fmaf(X, cs.x, fmaf(Y, cs.y, 256.0f));
            float fi = floorf(p);
            float w  = p - fi;
            half2_t wp = __builtin_amdgcn_cvt_pkrtz(1.0f - w, w);
            size_t idx = ((size_t)a << 9) + (int)fi;
            uint4 lo = plo[idx];
            uint4 hi = phi[idx];
            acc0 = dot2(lo.x, wp, acc0);
            acc1 = dot2(lo.y, wp, acc1);
            acc2 = dot2(lo.z, wp, acc2);
            acc3 = dot2(lo.w, wp, acc3);
            acc4 = dot2(hi.x, wp, acc4);
            acc5 = dot2(hi.y, wp, acc5);
            acc6 = dot2(hi.z, wp, acc6);
            acc7 = dot2(hi.w, wp, acc7);
        }
    } else {
        // ================= LDS-gather path (R9 structure) ================
        int A0 = slot * CHA;                // 0 or 288
        const int len = CHA;                // 288, %8 == 0
        int ngrp = len >> 3;

        // per-angle window bases (corner-min p, 2-cell guard) + tab copy
        float Xa = fmaf((float)(TOP + bi * 16),      step, -0.13f);
        float Xb = fmaf((float)(TOP + bi * 16 + 15), step, -0.13f);
        float Ya = fmaf((float)(TOP + bj * 16),      step, -0.13f);
        float Yb = fmaf((float)(TOP + bj * 16 + 15), step, -0.13f);
        for (int aidx = tid; aidx < len; aidx += 256) {
            float2 cs = g_tab[A0 + aidx];
            s_tab[aidx] = cs;
            float p0 = fmaf(Xa, cs.x, fmaf(Ya, cs.y, 256.0f));
            float p1 = fmaf(Xb, cs.x, fmaf(Ya, cs.y, 256.0f));
            float p2 = fmaf(Xa, cs.x, fmaf(Yb, cs.y, 256.0f));
            float p3 = fmaf(Xb, cs.x, fmaf(Yb, cs.y, 256.0f));
            float pm = fminf(fminf(p0, p1), fminf(p2, p3)) - 2.0f;
            int b = (int)floorf(pm);
            b = b < 0 ? 0 : b;
            b = b > (ND2 - WIN) ? (ND2 - WIN) : b;   // [0, 480]
            s_base[aidx] = b;
        }
        __syncthreads();

        // staging address pieces (thread stages cell sl of group-angle sk)
        int sk = tid >> 5, sl = tid & 31;

        // prologue: stage group 0 into buffer 0
        {
            size_t idx = (size_t)(A0 + sk) * ND2 + s_base[sk] + sl;
            s_lo[0][tid] = g_plo[idx];
            s_hi[0][tid] = g_phi[idx];
        }
        __syncthreads();

#define BODY(K, BASE, CC, SS)                                           \
        {                                                               \
            float p  = fmaf(X, CC, fmaf(Y, SS, 256.0f));                \
            float fi = floorf(p);                                       \
            float w  = p - fi;                                          \
            half2_t wp = __builtin_amdgcn_cvt_pkrtz(1.0f - w, w);       \
            int l = (int)fi - (BASE);                                   \
            uint4 lo = blo[(K) * WIN + l];                              \
            uint4 hi = bhi[(K) * WIN + l];                              \
            acc0 = dot2(lo.x, wp, acc0);                                \
            acc1 = dot2(lo.y, wp, acc1);                                \
            acc2 = dot2(lo.z, wp, acc2);                                \
            acc3 = dot2(lo.w, wp, acc3);                                \
            acc4 = dot2(hi.x, wp, acc4);                                \
            acc5 = dot2(hi.y, wp, acc5);                                \
            acc6 = dot2(hi.z, wp, acc6);                                \
            acc7 = dot2(hi.w, wp, acc7);                                \
        }

        for (int g = 0; g < ngrp; ++g) {
            int cur = g & 1;
            bool have = (g + 1) < ngrp;
            uint4 r0, r1;
            if (have) {
                int ag = (g + 1) * GRP + sk;
                size_t idx = (size_t)(A0 + ag) * ND2 + s_base[ag] + sl;
                r0 = g_plo[idx];
                r1 = g_phi[idx];
            }

            const uint4* blo = s_lo[cur];
            const uint4* bhi = s_hi[cur];
            int gb = g * GRP;

            // uniform per-group broadcasts: 8 bases + 4 (cos,sin); rotate +4
            int4  b4a = *(const int4*)(s_base + gb);
            int4  b4b = *(const int4*)(s_base + gb + 4);
            float4 t01 = *(const float4*)(s_tab + gb);
            float4 t23 = *(const float4*)(s_tab + gb + 2);
            float c_0 = t01.x, s_0 = t01.y, c_1 = t01.z, s_1 = t01.w;
            float c_2 = t23.x, s_2 = t23.y, c_3 = t23.z, s_3 = t23.w;
            float c_4 = fmaf(c_0, C4R, -(s_0 * S4R)), s_4 = fmaf(c_0, S4R, s_0 * C4R);
            float c_5 = fmaf(c_1, C4R, -(s_1 * S4R)), s_5 = fmaf(c_1, S4R, s_1 * C4R);
            float c_6 = fmaf(c_2, C4R, -(s_2 * S4R)), s_6 = fmaf(c_2, S4R, s_2 * C4R);
            float c_7 = fmaf(c_3, C4R, -(s_3 * S4R)), s_7 = fmaf(c_3, S4R, s_3 * C4R);

            BODY(0, b4a.x, c_0, s_0)
            BODY(1, b4a.y, c_1, s_1)
            BODY(2, b4a.z, c_2, s_2)
            BODY(3, b4a.w, c_3, s_3)
            BODY(4, b4b.x, c_4, s_4)
            BODY(5, b4b.y, c_5, s_5)
            BODY(6, b4b.z, c_6, s_6)
            BODY(7, b4b.w, c_7, s_7)

            if (have) {
                int nxt = cur ^ 1;
                s_lo[nxt][tid] = r0;
                s_hi[nxt][tid] = r1;
            }
            __syncthreads();
        }
#undef BODY
    }

    if (i < CROP && j < CROP) {
        float* p0 = g_part + (size_t)slot * 8 * NPIX + (size_t)i * CROP + j;
        p0[0 * NPIX] = acc0; p0[1 * NPIX] = acc1;
        p0[2 * NPIX] = acc2; p0[3 * NPIX] = acc3;
        p0[4 * NPIX] = acc4; p0[5 * NPIX] = acc5;
        p0[6 * NPIX] = acc6; p0[7 * NPIX] = acc7;
    }
}

// out[b][pix] = sum_slot part[slot][b][pix] * pi/NA
__global__ void combine_kernel(float* __restrict__ out) {
    int t = blockIdx.x * 256 + threadIdx.x;      // t over 8*NPIX, batch-major
    if (t >= 8 * NPIX) return;
    const float scale = (float)(3.14159265358979323846 / 1000.0);
    float s = 0.f;
    #pragma unroll
    for (int ch = 0; ch < 3; ++ch) s += g_part[(size_t)ch * 8 * NPIX + t];
    out[t] = s * scale;
}

extern "C" void kernel_launch(void* const* d_in, const int* in_sizes, int n_in,
                              void* d_out, int out_size, void* d_ws, size_t ws_size,
                              hipStream_t stream) {
    const float* x = (const float*)d_in[0];
    float* out = (float*)d_out;

    table_kernel<<<(NA + 255) / 256, 256, 0, stream>>>();
    pack_kernel<<<(NA * ND2 + 255) / 256, 256, 0, stream>>>(x);

    dim3 bgrid(3, NTILE, NTILE);   // x = slot: interleaved 2 LDS : 1 L1
    bp_kernel<<<bgrid, 256, 0, stream>>>();

    combine_kernel<<<(8 * NPIX + 255) / 256, 256, 0, stream>>>(out);
}